// Round 1
// baseline (180.365 us; speedup 1.0000x reference)
//
#include <hip/hip_runtime.h>
#include <hip/hip_bf16.h>

// Shapes (fixed by setup_inputs): bs=8, v=2048, n=20, inc=64, outc=128, sup=2
#define BS    8
#define V     2048
#define NNB   20
#define INC   64
#define OUTC  128
#define SUP   2
#define NCOL  ((SUP + 1) * OUTC)   // 384
#define SCOL  (SUP * OUTC)         // 256
#define ROWS  (BS * V)             // 16384

// ---------------------------------------------------------------------------
// K1: feat = feature_map @ weights + bias  -> center (ROWS x 128), support (ROWS x 256)
// Block: 384 threads (col per thread), 32 rows per block, features staged in LDS.
// ---------------------------------------------------------------------------
__global__ __launch_bounds__(384) void k_feat(const float* __restrict__ fm,
                                              const float* __restrict__ W,
                                              const float* __restrict__ bias,
                                              float* __restrict__ center,
                                              float* __restrict__ support) {
    const int rows0 = blockIdx.x * 32;
    const int c = threadIdx.x;            // 0..383
    __shared__ float lds[32][INC];        // 8 KB

    for (int i = threadIdx.x; i < 32 * INC; i += 384)
        lds[i >> 6][i & 63] = fm[rows0 * INC + i];
    __syncthreads();

    float acc[32];
#pragma unroll
    for (int r = 0; r < 32; ++r) acc[r] = 0.f;

    for (int k = 0; k < INC; k += 4) {
        const float w0 = W[(k + 0) * NCOL + c];
        const float w1 = W[(k + 1) * NCOL + c];
        const float w2 = W[(k + 2) * NCOL + c];
        const float w3 = W[(k + 3) * NCOL + c];
#pragma unroll
        for (int r = 0; r < 32; ++r) {
            const float4 x = *reinterpret_cast<const float4*>(&lds[r][k]);
            acc[r] = fmaf(x.x, w0, acc[r]);
            acc[r] = fmaf(x.y, w1, acc[r]);
            acc[r] = fmaf(x.z, w2, acc[r]);
            acc[r] = fmaf(x.w, w3, acc[r]);
        }
    }

    const float bb = bias[c];
#pragma unroll
    for (int r = 0; r < 32; ++r) {
        const float val = acc[r] + bb;
        const int row = rows0 + r;
        if (c < OUTC) center[row * OUTC + c] = val;
        else          support[row * SCOL + (c - OUTC)] = val;
    }
}

// ---------------------------------------------------------------------------
// K2: per-vertex neighbor phase. One wave per vertex; lane owns 4 of 256 cols.
//     Writes X row = [fuse(128) || dist_sum(128)].
// Grid swizzle: batch = bid & 7 so each batch's 2MB support slice sticks to
// one XCD's L2 (8 batches == 8 XCDs, blocks round-robin across XCDs).
// ---------------------------------------------------------------------------
__global__ __launch_bounds__(256) void k_neigh(const int*   __restrict__ nbr,
                                               const float* __restrict__ verts,
                                               const float* __restrict__ dirs,
                                               const float* __restrict__ dw,
                                               const float* __restrict__ center,
                                               const float* __restrict__ support,
                                               float* __restrict__ X) {
    const int bid   = blockIdx.x;
    const int batch = bid & 7;
    const int chunk = bid >> 3;             // 0..511
    const int wave  = threadIdx.x >> 6;     // 0..3
    const int lane  = threadIdx.x & 63;
    const int u     = chunk * 4 + wave;     // 0..2047
    const int row   = batch * V + u;

    // normalized spatial directions + distance weights for my 4 columns
    float sd0[4], sd1[4], sd2[4], dwv[4];
#pragma unroll
    for (int q = 0; q < 4; ++q) {
        const int col = lane + q * 64;
        const float d0 = dirs[0 * SCOL + col];
        const float d1 = dirs[1 * SCOL + col];
        const float d2 = dirs[2 * SCOL + col];
        const float inv = 1.0f / fmaxf(sqrtf(d0 * d0 + d1 * d1 + d2 * d2), 1e-12f);
        sd0[q] = d0 * inv; sd1[q] = d1 * inv; sd2[q] = d2 * inv;
        dwv[q] = dw[col];
    }

    const float vx = verts[row * 3 + 0];
    const float vy = verts[row * 3 + 1];
    const float vz = verts[row * 3 + 2];

    float m[4] = { -INFINITY, -INFINITY, -INFINITY, -INFINITY };
    float dmax = 0.f;  // dists are >= 0, so 0-init == true max

    for (int j = 0; j < NNB; ++j) {
        const int g = nbr[row * NNB + j];                 // wave-uniform
        const float* npos = &verts[(batch * V + g) * 3];
        const float dx = npos[0] - vx, dy = npos[1] - vy, dz = npos[2] - vz;
        const float dist = sqrtf(dx * dx + dy * dy + dz * dz);
        dmax = fmaxf(dmax, dist);
        const float inv = 1.0f / fmaxf(dist, 1e-12f);
        const float nx = dx * inv, ny = dy * inv, nz = dz * inv;
        const float* sg = &support[(batch * V + g) * SCOL];
#pragma unroll
        for (int q = 0; q < 4; ++q) {
            const int col = lane + q * 64;
            const float th = fmaxf(fmaf(nx, sd0[q], fmaf(ny, sd1[q], nz * sd2[q])), 0.f);
            m[q] = fmaxf(m[q], th * sg[col]);
        }
    }

    // fuse = center + sum_s max_n ;  dist_sum = sum_s relu(dmax*dw)
    const float c0 = center[row * OUTC + lane];
    const float c1 = center[row * OUTC + 64 + lane];
    const float fuse0 = c0 + m[0] + m[2];         // oc = lane      (s=0 col=lane, s=1 col=128+lane)
    const float fuse1 = c1 + m[1] + m[3];         // oc = 64+lane
    const float df0 = fmaxf(dmax * dwv[0], 0.f);
    const float df1 = fmaxf(dmax * dwv[1], 0.f);
    const float df2 = fmaxf(dmax * dwv[2], 0.f);
    const float df3 = fmaxf(dmax * dwv[3], 0.f);

    float* xr = &X[row * SCOL];
    xr[lane]       = fuse0;
    xr[64 + lane]  = fuse1;
    xr[128 + lane] = df0 + df2;
    xr[192 + lane] = df1 + df3;
}

// ---------------------------------------------------------------------------
// K3: out = X (ROWS x 256) @ mlp_w.T (256 x 128) + mlp_b
// Block: 256 threads = 128 oc x 2 row-halves, 32 rows staged in LDS (32 KB).
// ---------------------------------------------------------------------------
__global__ __launch_bounds__(256) void k_out(const float* __restrict__ X,
                                             const float* __restrict__ Wm,
                                             const float* __restrict__ bm,
                                             float* __restrict__ out) {
    const int rows0 = blockIdx.x * 32;
    __shared__ float lds[32 * SCOL];      // 32 KB

    for (int i = threadIdx.x; i < 32 * SCOL; i += 256)
        lds[i] = X[rows0 * SCOL + i];
    __syncthreads();

    const int oc   = threadIdx.x & 127;
    const int half = threadIdx.x >> 7;    // rows 0..15 / 16..31

    float acc[16];
#pragma unroll
    for (int r = 0; r < 16; ++r) acc[r] = 0.f;

    const float* wrow = &Wm[oc * SCOL];
    for (int j = 0; j < SCOL; j += 4) {
        const float4 w = *reinterpret_cast<const float4*>(&wrow[j]);
#pragma unroll
        for (int r = 0; r < 16; ++r) {
            const float4 x = *reinterpret_cast<const float4*>(&lds[(half * 16 + r) * SCOL + j]);
            acc[r] = fmaf(x.x, w.x, acc[r]);
            acc[r] = fmaf(x.y, w.y, acc[r]);
            acc[r] = fmaf(x.z, w.z, acc[r]);
            acc[r] = fmaf(x.w, w.w, acc[r]);
        }
    }

    const float bb = bm[oc];
#pragma unroll
    for (int r = 0; r < 16; ++r)
        out[(rows0 + half * 16 + r) * OUTC + oc] = acc[r] + bb;
}

// ---------------------------------------------------------------------------
extern "C" void kernel_launch(void* const* d_in, const int* in_sizes, int n_in,
                              void* d_out, int out_size, void* d_ws, size_t ws_size,
                              hipStream_t stream) {
    const int*   nbr   = (const int*)  d_in[0];
    const float* verts = (const float*)d_in[1];
    const float* fm    = (const float*)d_in[2];
    const float* W     = (const float*)d_in[3];
    const float* bias  = (const float*)d_in[4];
    const float* dirs  = (const float*)d_in[5];
    const float* dw    = (const float*)d_in[6];
    const float* Wm    = (const float*)d_in[7];
    const float* bm    = (const float*)d_in[8];
    float* out = (float*)d_out;

    // workspace layout
    float* center  = (float*)d_ws;                          //  8 MB (ROWS*128)
    float* support = center + (size_t)ROWS * OUTC;          // 16 MB (ROWS*256)
    float* X       = support + (size_t)ROWS * SCOL;         // 16 MB (ROWS*256)

    k_feat <<<ROWS / 32, 384, 0, stream>>>(fm, W, bias, center, support);
    k_neigh<<<ROWS / 4, 256, 0, stream>>>(nbr, verts, dirs, dw, center, support, X);
    k_out  <<<ROWS / 32, 256, 0, stream>>>(X, Wm, bm, out);
}

// Round 2
// 156.475 us; speedup vs baseline: 1.1527x; 1.1527x over previous
//
#include <hip/hip_runtime.h>
#include <hip/hip_bf16.h>

// Shapes (fixed by setup_inputs): bs=8, v=2048, n=20, inc=64, outc=128, sup=2
#define BS    8
#define V     2048
#define NNB   20
#define INC   64
#define OUTC  128
#define SUP   2
#define NCOL  ((SUP + 1) * OUTC)   // 384
#define SCOL  (SUP * OUTC)         // 256
#define ROWS  (BS * V)             // 16384

// ---------------------------------------------------------------------------
// K1: feat = feature_map @ weights + bias -> center (ROWS x 128), support (ROWS x 256)
// 384 threads (col/thread), 16 rows/block -> 1024 blocks (4 blk/CU, 24 waves/CU).
// ---------------------------------------------------------------------------
#define K1_ROWS 16
__global__ __launch_bounds__(384) void k_feat(const float* __restrict__ fm,
                                              const float* __restrict__ W,
                                              const float* __restrict__ bias,
                                              float* __restrict__ center,
                                              float* __restrict__ support) {
    const int rows0 = blockIdx.x * K1_ROWS;
    const int c = threadIdx.x;            // 0..383
    __shared__ float lds[K1_ROWS][INC];   // 4 KB

    if (threadIdx.x < (K1_ROWS * INC / 4))   // 256 float4s
        reinterpret_cast<float4*>(&lds[0][0])[threadIdx.x] =
            reinterpret_cast<const float4*>(fm + (size_t)rows0 * INC)[threadIdx.x];
    __syncthreads();

    float acc[K1_ROWS];
#pragma unroll
    for (int r = 0; r < K1_ROWS; ++r) acc[r] = 0.f;

#pragma unroll 4
    for (int k = 0; k < INC; k += 4) {
        const float w0 = W[(k + 0) * NCOL + c];
        const float w1 = W[(k + 1) * NCOL + c];
        const float w2 = W[(k + 2) * NCOL + c];
        const float w3 = W[(k + 3) * NCOL + c];
#pragma unroll
        for (int r = 0; r < K1_ROWS; ++r) {
            const float4 x = *reinterpret_cast<const float4*>(&lds[r][k]);
            acc[r] = fmaf(x.x, w0, acc[r]);
            acc[r] = fmaf(x.y, w1, acc[r]);
            acc[r] = fmaf(x.z, w2, acc[r]);
            acc[r] = fmaf(x.w, w3, acc[r]);
        }
    }

    const float bb = bias[c];
#pragma unroll
    for (int r = 0; r < K1_ROWS; ++r) {
        const float val = acc[r] + bb;
        const int row = rows0 + r;
        if (c < OUTC) center[(size_t)row * OUTC + c] = val;
        else          support[(size_t)row * SCOL + (c - OUTC)] = val;
    }
}

// ---------------------------------------------------------------------------
// K2: per-vertex neighbor phase. 2 vertices per wave (32 lanes each, 8 cols/lane).
// Block 256 = 4 waves = 8 vertices -> 2048 blocks. batch = bid&7 (XCD swizzle:
// each batch's 2MB support slice sticks to one XCD's L2).
// ---------------------------------------------------------------------------
__global__ __launch_bounds__(256) void k_neigh(const int*   __restrict__ nbr,
                                               const float* __restrict__ verts,
                                               const float* __restrict__ dirs,
                                               const float* __restrict__ dw,
                                               const float* __restrict__ center,
                                               const float* __restrict__ support,
                                               float* __restrict__ X) {
    const int bid   = blockIdx.x;
    const int batch = bid & 7;
    const int chunk = bid >> 3;             // 0..255
    const int wid   = threadIdx.x >> 6;     // 0..3
    const int lane  = threadIdx.x & 63;
    const int half  = lane >> 5;
    const int sl    = lane & 31;
    const int u     = chunk * 8 + wid * 2 + half;   // 0..2047
    const int bV    = batch * V;
    const int row   = bV + u;

    // normalized spatial directions + distance weights for my 8 columns (sl + q*32)
    float sd0[8], sd1[8], sd2[8], dwv[8];
#pragma unroll
    for (int q = 0; q < 8; ++q) {
        const int col = sl + q * 32;
        const float d0 = dirs[0 * SCOL + col];
        const float d1 = dirs[1 * SCOL + col];
        const float d2c = dirs[2 * SCOL + col];
        // 1/max(sqrt(x),1e-12) == rsq(max(x,1e-24))
        const float inv = __builtin_amdgcn_rsqf(fmaxf(fmaf(d0, d0, fmaf(d1, d1, d2c * d2c)), 1e-24f));
        sd0[q] = d0 * inv; sd1[q] = d1 * inv; sd2[q] = d2c * inv;
        dwv[q] = dw[col];
    }

    const float vx = verts[row * 3 + 0];
    const float vy = verts[row * 3 + 1];
    const float vz = verts[row * 3 + 2];

    // prefetch all 20 neighbor indices (row*80 bytes is 16B-aligned)
    int gs[NNB];
    {
        const int4* np4 = reinterpret_cast<const int4*>(nbr + (size_t)row * NNB);
#pragma unroll
        for (int t = 0; t < 5; ++t) {
            const int4 g4 = np4[t];
            gs[t * 4 + 0] = g4.x; gs[t * 4 + 1] = g4.y;
            gs[t * 4 + 2] = g4.z; gs[t * 4 + 3] = g4.w;
        }
    }

    float m[8];
#pragma unroll
    for (int q = 0; q < 8; ++q) m[q] = -INFINITY;
    float d2max = 0.f;   // max(dist) == sqrt(max(dist^2))

#pragma unroll
    for (int j = 0; j < NNB; ++j) {
        const int g = bV + gs[j];
        const float px = verts[g * 3 + 0];
        const float py = verts[g * 3 + 1];
        const float pz = verts[g * 3 + 2];
        const float dx = px - vx, dy = py - vy, dz = pz - vz;
        const float d2 = fmaf(dx, dx, fmaf(dy, dy, dz * dz));
        d2max = fmaxf(d2max, d2);
        const float inv = __builtin_amdgcn_rsqf(fmaxf(d2, 1e-24f));  // == 1/max(dist,1e-12)
        const float nx = dx * inv, ny = dy * inv, nz = dz * inv;
        const float* sg = support + (size_t)g * SCOL;
#pragma unroll
        for (int q = 0; q < 8; ++q) {
            const float th = fmaxf(fmaf(nx, sd0[q], fmaf(ny, sd1[q], nz * sd2[q])), 0.f);
            m[q] = fmaxf(m[q], th * sg[sl + q * 32]);
        }
    }
    const float dmax = sqrtf(d2max);

    // fuse[oc] = center[oc] + m_s0[oc] + m_s1[oc];  oc = sl + q*32, q=0..3
    // dist_sum[oc] = relu(dmax*dw[oc]) + relu(dmax*dw[128+oc])
    const float* cr = center + (size_t)row * OUTC;
    float* xr = X + (size_t)row * SCOL;
#pragma unroll
    for (int q = 0; q < 4; ++q) {
        const float fuse = cr[sl + q * 32] + m[q] + m[q + 4];
        const float df = fmaxf(dmax * dwv[q], 0.f) + fmaxf(dmax * dwv[q + 4], 0.f);
        xr[sl + q * 32]        = fuse;
        xr[OUTC + sl + q * 32] = df;
    }
}

// ---------------------------------------------------------------------------
// K3: out = X (ROWS x 256) @ mlp_w.T (256 x 128) + mlp_b
// 256 threads = 128 oc x 2 row-halves, 16 rows/block -> 1024 blocks.
// ---------------------------------------------------------------------------
#define K3_ROWS 16
__global__ __launch_bounds__(256) void k_out(const float* __restrict__ X,
                                             const float* __restrict__ Wm,
                                             const float* __restrict__ bm,
                                             float* __restrict__ out) {
    const int rows0 = blockIdx.x * K3_ROWS;
    __shared__ float lds[K3_ROWS * SCOL];     // 16 KB

#pragma unroll
    for (int t = 0; t < 4; ++t)
        reinterpret_cast<float4*>(lds)[threadIdx.x + t * 256] =
            reinterpret_cast<const float4*>(X + (size_t)rows0 * SCOL)[threadIdx.x + t * 256];
    __syncthreads();

    const int oc   = threadIdx.x & 127;
    const int half = threadIdx.x >> 7;        // rows 0..7 / 8..15

    float acc[8];
#pragma unroll
    for (int r = 0; r < 8; ++r) acc[r] = 0.f;

    const float* wrow = &Wm[(size_t)oc * SCOL];
#pragma unroll 4
    for (int j = 0; j < SCOL; j += 4) {
        const float4 w = *reinterpret_cast<const float4*>(&wrow[j]);
#pragma unroll
        for (int r = 0; r < 8; ++r) {
            const float4 x = *reinterpret_cast<const float4*>(&lds[(half * 8 + r) * SCOL + j]);
            acc[r] = fmaf(x.x, w.x, acc[r]);
            acc[r] = fmaf(x.y, w.y, acc[r]);
            acc[r] = fmaf(x.z, w.z, acc[r]);
            acc[r] = fmaf(x.w, w.w, acc[r]);
        }
    }

    const float bb = bm[oc];
#pragma unroll
    for (int r = 0; r < 8; ++r)
        out[(size_t)(rows0 + half * 8 + r) * OUTC + oc] = acc[r] + bb;
}

// ---------------------------------------------------------------------------
extern "C" void kernel_launch(void* const* d_in, const int* in_sizes, int n_in,
                              void* d_out, int out_size, void* d_ws, size_t ws_size,
                              hipStream_t stream) {
    const int*   nbr   = (const int*)  d_in[0];
    const float* verts = (const float*)d_in[1];
    const float* fm    = (const float*)d_in[2];
    const float* W     = (const float*)d_in[3];
    const float* bias  = (const float*)d_in[4];
    const float* dirs  = (const float*)d_in[5];
    const float* dw    = (const float*)d_in[6];
    const float* Wm    = (const float*)d_in[7];
    const float* bm    = (const float*)d_in[8];
    float* out = (float*)d_out;

    // workspace layout
    float* center  = (float*)d_ws;                          //  8 MB (ROWS*128)
    float* support = center + (size_t)ROWS * OUTC;          // 16 MB (ROWS*256)
    float* X       = support + (size_t)ROWS * SCOL;         // 16 MB (ROWS*256)

    k_feat <<<ROWS / K1_ROWS, 384, 0, stream>>>(fm, W, bias, center, support);
    k_neigh<<<ROWS / 8,       256, 0, stream>>>(nbr, verts, dirs, dw, center, support, X);
    k_out  <<<ROWS / K3_ROWS, 256, 0, stream>>>(X, Wm, bm, out);
}

// Round 3
// 136.056 us; speedup vs baseline: 1.3257x; 1.1501x over previous
//
#include <hip/hip_runtime.h>
#include <hip/hip_bf16.h>

// Shapes (fixed by setup_inputs): bs=8, v=2048, n=20, inc=64, outc=128, sup=2
#define BS    8
#define V     2048
#define NNB   20
#define INC   64
#define OUTC  128
#define SUP   2
#define NCOL  ((SUP + 1) * OUTC)   // 384
#define SCOL  (SUP * OUTC)         // 256
#define ROWS  (BS * V)             // 16384

using bf16x8 = __bf16 __attribute__((ext_vector_type(8)));
using bf16x4 = __bf16 __attribute__((ext_vector_type(4)));
using f32x4  = float  __attribute__((ext_vector_type(4)));
using i32x4  = int    __attribute__((ext_vector_type(4)));

static __device__ inline bf16x8 cvt8(f32x4 lo, f32x4 hi) {
    bf16x8 r;
    r[0] = (__bf16)lo[0]; r[1] = (__bf16)lo[1]; r[2] = (__bf16)lo[2]; r[3] = (__bf16)lo[3];
    r[4] = (__bf16)hi[0]; r[5] = (__bf16)hi[1]; r[6] = (__bf16)hi[2]; r[7] = (__bf16)hi[3];
    return r;
}

// ---------------------------------------------------------------------------
// K0: prep — W_T bf16 [384][64], Wm1 bf16 [128][128], w2[128] = Wm2 @ u
//     where u[k] = relu(dw[k]) + relu(dw[128+k])  (valid since dmax >= 0).
// ---------------------------------------------------------------------------
__global__ __launch_bounds__(256) void k_prep(const float* __restrict__ W,
                                              const float* __restrict__ Wm,
                                              const float* __restrict__ dw,
                                              __bf16* __restrict__ WTb,
                                              __bf16* __restrict__ Wm1b,
                                              float* __restrict__ w2) {
    const int b = blockIdx.x;
    if (b < 96) {                       // transpose+cast W: [64][384] -> [384][64]
        const int idx = b * 256 + threadIdx.x;      // < 24576
        const int k = idx / NCOL, c = idx % NCOL;
        WTb[c * INC + k] = (__bf16)W[idx];
    } else if (b < 160) {               // cast Wm[:, :128] -> bf16 [o][k]
        const int idx = (b - 96) * 256 + threadIdx.x;   // < 16384
        const int o = idx >> 7, k = idx & 127;
        Wm1b[idx] = (__bf16)Wm[o * SCOL + k];
    } else {                            // u + w2
        __shared__ float u[OUTC];
        const int t = threadIdx.x;
        if (t < OUTC) u[t] = fmaxf(dw[t], 0.f) + fmaxf(dw[OUTC + t], 0.f);
        __syncthreads();
        if (t < OUTC) {
            float s = 0.f;
            for (int k = 0; k < OUTC; ++k) s = fmaf(Wm[t * SCOL + OUTC + k], u[k], s);
            w2[t] = s;
        }
    }
}

// ---------------------------------------------------------------------------
// K1: feat = fm @ W + bias (MFMA bf16). Block = 4 waves, 16 rows x 384 cols.
// Wave w: cols w*96..w*96+95 (6 tiles of 16), K=64 = 2 k-frags.
// ---------------------------------------------------------------------------
__global__ __launch_bounds__(256) void k_feat(const float* __restrict__ fm,
                                              const __bf16* __restrict__ WTb,
                                              const float* __restrict__ bias,
                                              float* __restrict__ center,
                                              float* __restrict__ support) {
    const int row0 = blockIdx.x * 16;
    const int wid = threadIdx.x >> 6, lane = threadIdx.x & 63;
    const int ln = lane & 15, lg = lane >> 4;
    const int cbase = wid * 96;

    // A frags: A[m=row0+ln][k = kf*32 + lg*8 + j]
    const float* ap = fm + (size_t)(row0 + ln) * INC + lg * 8;
    const bf16x8 a0 = cvt8(*(const f32x4*)(ap +  0), *(const f32x4*)(ap +  4));
    const bf16x8 a1 = cvt8(*(const f32x4*)(ap + 32), *(const f32x4*)(ap + 36));

    f32x4 acc[6];
#pragma unroll
    for (int t = 0; t < 6; ++t) acc[t] = (f32x4)0.f;

    // B frags: B[k][n=col0+ln] = WTb[col0+ln][k], 8 consecutive bf16
    const __bf16* bp = WTb + (size_t)(cbase + ln) * INC + lg * 8;
#pragma unroll
    for (int t = 0; t < 6; ++t) {
        const bf16x8 b0 = *(const bf16x8*)(bp + t * 16 * INC);
        const bf16x8 b1 = *(const bf16x8*)(bp + t * 16 * INC + 32);
        acc[t] = __builtin_amdgcn_mfma_f32_16x16x32_bf16(a0, b0, acc[t], 0, 0, 0);
        acc[t] = __builtin_amdgcn_mfma_f32_16x16x32_bf16(a1, b1, acc[t], 0, 0, 0);
    }

    // C: col = lane&15, row = (lane>>4)*4 + r  [verified layout]
#pragma unroll
    for (int t = 0; t < 6; ++t) {
        const int col = cbase + t * 16 + ln;
        const float bb = bias[col];
        const int r0 = row0 + lg * 4;
        if (col < OUTC) {
#pragma unroll
            for (int r = 0; r < 4; ++r)
                center[(size_t)(r0 + r) * OUTC + col] = acc[t][r] + bb;
        } else {
            const int sc = col - OUTC;
#pragma unroll
            for (int r = 0; r < 4; ++r)
                support[(size_t)(r0 + r) * SCOL + sc] = acc[t][r] + bb;
        }
    }
}

// ---------------------------------------------------------------------------
// K2: neighbor phase. 2 vertices/wave (32 lanes each); lane sl owns cols
// sl*4..sl*4+3 of each support half -> float4 gathers. Writes fuse (bf16) + dmax.
// batch = bid&7 XCD swizzle (batch's 2MB support slice sticks to one XCD L2).
// ---------------------------------------------------------------------------
__global__ __launch_bounds__(256) void k_neigh(const int*   __restrict__ nbr,
                                               const float* __restrict__ verts,
                                               const float* __restrict__ dirs,
                                               const float* __restrict__ center,
                                               const float* __restrict__ support,
                                               __bf16* __restrict__ Xb,
                                               float* __restrict__ dmaxv) {
    const int bid   = blockIdx.x;
    const int batch = bid & 7;
    const int chunk = bid >> 3;
    const int wid   = threadIdx.x >> 6;
    const int lane  = threadIdx.x & 63;
    const int half  = lane >> 5;
    const int sl    = lane & 31;
    const int u     = chunk * 8 + wid * 2 + half;
    const int bV    = batch * V;
    const int row   = bV + u;
    const int c0    = sl * 4;

    // normalized spatial directions for my 8 cols (4 per support half)
    f32x4 a0 = *(const f32x4*)(dirs +            c0);
    f32x4 a1 = *(const f32x4*)(dirs + SCOL +     c0);
    f32x4 a2 = *(const f32x4*)(dirs + 2*SCOL +   c0);
    f32x4 b0 = *(const f32x4*)(dirs +            OUTC + c0);
    f32x4 b1 = *(const f32x4*)(dirs + SCOL +     OUTC + c0);
    f32x4 b2 = *(const f32x4*)(dirs + 2*SCOL +   OUTC + c0);
#pragma unroll
    for (int j = 0; j < 4; ++j) {
        float inv = __builtin_amdgcn_rsqf(fmaxf(fmaf(a0[j], a0[j], fmaf(a1[j], a1[j], a2[j]*a2[j])), 1e-24f));
        a0[j] *= inv; a1[j] *= inv; a2[j] *= inv;
        inv = __builtin_amdgcn_rsqf(fmaxf(fmaf(b0[j], b0[j], fmaf(b1[j], b1[j], b2[j]*b2[j])), 1e-24f));
        b0[j] *= inv; b1[j] *= inv; b2[j] *= inv;
    }

    const float vx = verts[row * 3 + 0];
    const float vy = verts[row * 3 + 1];
    const float vz = verts[row * 3 + 2];

    int gs[NNB];
    {
        const i32x4* np4 = reinterpret_cast<const i32x4*>(nbr + (size_t)row * NNB);
#pragma unroll
        for (int t = 0; t < 5; ++t) {
            const i32x4 g4 = np4[t];
            gs[t*4+0] = g4[0]; gs[t*4+1] = g4[1]; gs[t*4+2] = g4[2]; gs[t*4+3] = g4[3];
        }
    }

    f32x4 m0, m1;
#pragma unroll
    for (int j = 0; j < 4; ++j) { m0[j] = -INFINITY; m1[j] = -INFINITY; }
    float d2max = 0.f;

#pragma unroll
    for (int j = 0; j < NNB; ++j) {
        const int g = bV + gs[j];
        const float px = verts[g * 3 + 0];
        const float py = verts[g * 3 + 1];
        const float pz = verts[g * 3 + 2];
        const float dx = px - vx, dy = py - vy, dz = pz - vz;
        const float d2 = fmaf(dx, dx, fmaf(dy, dy, dz * dz));
        d2max = fmaxf(d2max, d2);
        const float inv = __builtin_amdgcn_rsqf(fmaxf(d2, 1e-24f));  // == 1/max(dist,1e-12)
        const float nx = dx * inv, ny = dy * inv, nz = dz * inv;
        const float* sg = support + (size_t)g * SCOL + c0;
        const f32x4 s0 = *(const f32x4*)(sg);
        const f32x4 s1 = *(const f32x4*)(sg + OUTC);
#pragma unroll
        for (int jj = 0; jj < 4; ++jj) {
            const float t0 = fmaxf(fmaf(nx, a0[jj], fmaf(ny, a1[jj], nz * a2[jj])), 0.f);
            const float t1 = fmaxf(fmaf(nx, b0[jj], fmaf(ny, b1[jj], nz * b2[jj])), 0.f);
            m0[jj] = fmaxf(m0[jj], t0 * s0[jj]);
            m1[jj] = fmaxf(m1[jj], t1 * s1[jj]);
        }
    }

    const f32x4 cc = *(const f32x4*)(center + (size_t)row * OUTC + c0);
    bf16x4 fx;
#pragma unroll
    for (int jj = 0; jj < 4; ++jj) fx[jj] = (__bf16)(cc[jj] + m0[jj] + m1[jj]);
    *(bf16x4*)(Xb + (size_t)row * OUTC + c0) = fx;
    if (sl == 0) dmaxv[row] = sqrtf(d2max);
}

// ---------------------------------------------------------------------------
// K3: out = fuse @ Wm1^T + dmax*w2 + mlp_b (MFMA bf16, K=128).
// Block = 4 waves: wave w -> rows blk*32 + (w>>1)*16, cols (w&1)*64 (4 tiles).
// ---------------------------------------------------------------------------
__global__ __launch_bounds__(256) void k_out(const __bf16* __restrict__ Xb,
                                             const __bf16* __restrict__ Wm1b,
                                             const float* __restrict__ dmaxv,
                                             const float* __restrict__ w2,
                                             const float* __restrict__ mb,
                                             float* __restrict__ out) {
    const int wid = threadIdx.x >> 6, lane = threadIdx.x & 63;
    const int ln = lane & 15, lg = lane >> 4;
    const int row0 = blockIdx.x * 32 + (wid >> 1) * 16;
    const int cb = (wid & 1) * 64;

    const __bf16* ap = Xb + (size_t)(row0 + ln) * OUTC + lg * 8;
    bf16x8 a[4];
#pragma unroll
    for (int kf = 0; kf < 4; ++kf) a[kf] = *(const bf16x8*)(ap + kf * 32);

    f32x4 acc[4];
#pragma unroll
    for (int t = 0; t < 4; ++t) acc[t] = (f32x4)0.f;

    const __bf16* bp = Wm1b + (size_t)(cb + ln) * OUTC + lg * 8;
#pragma unroll
    for (int t = 0; t < 4; ++t) {
#pragma unroll
        for (int kf = 0; kf < 4; ++kf) {
            const bf16x8 b = *(const bf16x8*)(bp + t * 16 * OUTC + kf * 32);
            acc[t] = __builtin_amdgcn_mfma_f32_16x16x32_bf16(a[kf], b, acc[t], 0, 0, 0);
        }
    }

    float dm[4];
#pragma unroll
    for (int r = 0; r < 4; ++r) dm[r] = dmaxv[row0 + lg * 4 + r];

#pragma unroll
    for (int t = 0; t < 4; ++t) {
        const int col = cb + t * 16 + ln;
        const float w2c = w2[col];
        const float bb = mb[col];
#pragma unroll
        for (int r = 0; r < 4; ++r)
            out[(size_t)(row0 + lg * 4 + r) * OUTC + col] = fmaf(dm[r], w2c, acc[t][r] + bb);
    }
}

// ---------------------------------------------------------------------------
extern "C" void kernel_launch(void* const* d_in, const int* in_sizes, int n_in,
                              void* d_out, int out_size, void* d_ws, size_t ws_size,
                              hipStream_t stream) {
    const int*   nbr   = (const int*)  d_in[0];
    const float* verts = (const float*)d_in[1];
    const float* fm    = (const float*)d_in[2];
    const float* W     = (const float*)d_in[3];
    const float* bias  = (const float*)d_in[4];
    const float* dirs  = (const float*)d_in[5];
    const float* dw    = (const float*)d_in[6];
    const float* Wm    = (const float*)d_in[7];
    const float* mb    = (const float*)d_in[8];
    float* out = (float*)d_out;

    // workspace layout (all 16B-aligned)
    float*  center  = (float*)d_ws;                         // 16384*128 f32
    float*  support = center + (size_t)ROWS * OUTC;         // 16384*256 f32
    __bf16* Xb      = (__bf16*)(support + (size_t)ROWS * SCOL);  // 16384*128 bf16
    float*  dmaxv   = (float*)(Xb + (size_t)ROWS * OUTC);   // 16384 f32
    __bf16* WTb     = (__bf16*)(dmaxv + ROWS);              // 384*64 bf16
    __bf16* Wm1b    = WTb + NCOL * INC;                     // 128*128 bf16
    float*  w2      = (float*)(Wm1b + OUTC * OUTC);         // 128 f32

    k_prep <<<161,        256, 0, stream>>>(W, Wm, dw, WTb, Wm1b, w2);
    k_feat <<<ROWS / 16,  256, 0, stream>>>(fm, WTb, bias, center, support);
    k_neigh<<<ROWS / 8,   256, 0, stream>>>(nbr, verts, dirs, center, support, Xb, dmaxv);
    k_out  <<<ROWS / 32,  256, 0, stream>>>(Xb, Wm1b, dmaxv, w2, mb, out);
}

// Round 4
// 122.583 us; speedup vs baseline: 1.4714x; 1.1099x over previous
//
#include <hip/hip_runtime.h>
#include <hip/hip_bf16.h>

// Shapes (fixed by setup_inputs): bs=8, v=2048, n=20, inc=64, outc=128, sup=2
#define BS    8
#define V     2048
#define NNB   20
#define INC   64
#define OUTC  128
#define SUP   2
#define NCOL  ((SUP + 1) * OUTC)   // 384
#define SCOL  (SUP * OUTC)         // 256
#define ROWS  (BS * V)             // 16384

using bf16x8 = __bf16 __attribute__((ext_vector_type(8)));
using bf16x4 = __bf16 __attribute__((ext_vector_type(4)));
using f32x4  = float  __attribute__((ext_vector_type(4)));
using f32x2  = float  __attribute__((ext_vector_type(2)));
using i32x4  = int    __attribute__((ext_vector_type(4)));

#if __has_builtin(__builtin_elementwise_fma)
static __device__ inline f32x2 efma(f32x2 a, f32x2 b, f32x2 c) { return __builtin_elementwise_fma(a, b, c); }
#else
static __device__ inline f32x2 efma(f32x2 a, f32x2 b, f32x2 c) {
    f32x2 r; r[0] = fmaf(a[0], b[0], c[0]); r[1] = fmaf(a[1], b[1], c[1]); return r;
}
#endif
#if __has_builtin(__builtin_elementwise_max)
static __device__ inline f32x2 emax(f32x2 a, f32x2 b) { return __builtin_elementwise_max(a, b); }
#else
static __device__ inline f32x2 emax(f32x2 a, f32x2 b) {
    f32x2 r; r[0] = fmaxf(a[0], b[0]); r[1] = fmaxf(a[1], b[1]); return r;
}
#endif

static __device__ inline bf16x8 cvt8(f32x4 lo, f32x4 hi) {
    bf16x8 r;
    r[0] = (__bf16)lo[0]; r[1] = (__bf16)lo[1]; r[2] = (__bf16)lo[2]; r[3] = (__bf16)lo[3];
    r[4] = (__bf16)hi[0]; r[5] = (__bf16)hi[1]; r[6] = (__bf16)hi[2]; r[7] = (__bf16)hi[3];
    return r;
}

// ---------------------------------------------------------------------------
// K0: prep — W_T bf16 [384][64] (coalesced writes), Wm1 bf16 [128][128],
//     w2[128] = Wm2 @ u where u[k] = relu(dw[k]) + relu(dw[128+k]) (dmax >= 0).
// ---------------------------------------------------------------------------
__global__ __launch_bounds__(256) void k_prep(const float* __restrict__ W,
                                              const float* __restrict__ Wm,
                                              const float* __restrict__ dw,
                                              __bf16* __restrict__ WTb,
                                              __bf16* __restrict__ Wm1b,
                                              float* __restrict__ w2) {
    const int b = blockIdx.x;
    if (b < 96) {                       // W: [64][384] -> WTb [384][64], writes coalesced
        const int idx = b * 256 + threadIdx.x;      // < 24576
        const int c = idx >> 6, k = idx & 63;
        WTb[idx] = (__bf16)W[k * NCOL + c];
    } else if (b < 160) {               // cast Wm[:, :128] -> bf16 [o][k]
        const int idx = (b - 96) * 256 + threadIdx.x;   // < 16384
        const int o = idx >> 7, k = idx & 127;
        Wm1b[idx] = (__bf16)Wm[o * SCOL + k];
    } else {                            // u + w2
        __shared__ float u[OUTC];
        const int t = threadIdx.x;
        if (t < OUTC) u[t] = fmaxf(dw[t], 0.f) + fmaxf(dw[OUTC + t], 0.f);
        __syncthreads();
        if (t < OUTC) {
            float s = 0.f;
            for (int k = 0; k < OUTC; ++k) s = fmaf(Wm[t * SCOL + OUTC + k], u[k], s);
            w2[t] = s;
        }
    }
}

// ---------------------------------------------------------------------------
// K1: feat = fm @ W + bias (MFMA bf16). Block = 4 waves, 32 rows x 384 cols.
// Wave w: cols w*96..+95 (6 tiles), 2 row-sets of 16 sharing each B fragment.
// Bias folded into accumulator init (MFMA C-in accumulates).
// ---------------------------------------------------------------------------
__global__ __launch_bounds__(256) void k_feat(const float* __restrict__ fm,
                                              const __bf16* __restrict__ WTb,
                                              const float* __restrict__ bias,
                                              float* __restrict__ center,
                                              float* __restrict__ support) {
    const int row0 = blockIdx.x * 32;
    const int wid = threadIdx.x >> 6, lane = threadIdx.x & 63;
    const int ln = lane & 15, lg = lane >> 4;
    const int cbase = wid * 96;

    // A frags: A[m][k = kf*32 + lg*8 + j], row-sets rs=0,1 -> rows row0+rs*16+ln
    bf16x8 a[2][2];
#pragma unroll
    for (int rs = 0; rs < 2; ++rs) {
        const float* ap = fm + (size_t)(row0 + rs * 16 + ln) * INC + lg * 8;
        a[rs][0] = cvt8(*(const f32x4*)(ap +  0), *(const f32x4*)(ap +  4));
        a[rs][1] = cvt8(*(const f32x4*)(ap + 32), *(const f32x4*)(ap + 36));
    }

    f32x4 acc[2][6];
#pragma unroll
    for (int t = 0; t < 6; ++t) {
        const float bb = bias[cbase + t * 16 + ln];
        acc[0][t] = (f32x4){bb, bb, bb, bb};
        acc[1][t] = acc[0][t];
    }

    const __bf16* bp = WTb + (size_t)(cbase + ln) * INC + lg * 8;
#pragma unroll
    for (int t = 0; t < 6; ++t) {
        const bf16x8 b0 = *(const bf16x8*)(bp + t * 16 * INC);
        const bf16x8 b1 = *(const bf16x8*)(bp + t * 16 * INC + 32);
        acc[0][t] = __builtin_amdgcn_mfma_f32_16x16x32_bf16(a[0][0], b0, acc[0][t], 0, 0, 0);
        acc[0][t] = __builtin_amdgcn_mfma_f32_16x16x32_bf16(a[0][1], b1, acc[0][t], 0, 0, 0);
        acc[1][t] = __builtin_amdgcn_mfma_f32_16x16x32_bf16(a[1][0], b0, acc[1][t], 0, 0, 0);
        acc[1][t] = __builtin_amdgcn_mfma_f32_16x16x32_bf16(a[1][1], b1, acc[1][t], 0, 0, 0);
    }

    // C: col = lane&15, row = (lane>>4)*4 + r
#pragma unroll
    for (int rs = 0; rs < 2; ++rs) {
        const int r0 = row0 + rs * 16 + lg * 4;
#pragma unroll
        for (int t = 0; t < 6; ++t) {
            const int col = cbase + t * 16 + ln;
            if (col < OUTC) {
#pragma unroll
                for (int r = 0; r < 4; ++r)
                    center[(size_t)(r0 + r) * OUTC + col] = acc[rs][t][r];
            } else {
                const int sc = col - OUTC;
#pragma unroll
                for (int r = 0; r < 4; ++r)
                    support[(size_t)(r0 + r) * SCOL + sc] = acc[rs][t][r];
            }
        }
    }
}

// ---------------------------------------------------------------------------
// K2: neighbor phase. 2 vertices/wave (32 lanes each); lane sl owns cols
// sl*4..+3 of each support half. Col math on f32x2 (v_pk_fma_f32 packing).
// batch = bid&7 XCD swizzle. Writes fuse (bf16) + dmax.
// ---------------------------------------------------------------------------
__global__ __launch_bounds__(256) void k_neigh(const int*   __restrict__ nbr,
                                               const float* __restrict__ verts,
                                               const float* __restrict__ dirs,
                                               const float* __restrict__ center,
                                               const float* __restrict__ support,
                                               __bf16* __restrict__ Xb,
                                               float* __restrict__ dmaxv) {
    const int bid   = blockIdx.x;
    const int batch = bid & 7;
    const int chunk = bid >> 3;
    const int wid   = threadIdx.x >> 6;
    const int lane  = threadIdx.x & 63;
    const int half  = lane >> 5;
    const int sl    = lane & 31;
    const int u     = chunk * 8 + wid * 2 + half;
    const int bV    = batch * V;
    const int row   = bV + u;
    const int c0    = sl * 4;

    // normalized spatial directions: half A cols c0..c0+3, half B cols 128+c0..
    f32x4 A0 = *(const f32x4*)(dirs +            c0);
    f32x4 A1 = *(const f32x4*)(dirs + SCOL +     c0);
    f32x4 A2 = *(const f32x4*)(dirs + 2*SCOL +   c0);
    f32x4 B0 = *(const f32x4*)(dirs +            OUTC + c0);
    f32x4 B1 = *(const f32x4*)(dirs + SCOL +     OUTC + c0);
    f32x4 B2 = *(const f32x4*)(dirs + 2*SCOL +   OUTC + c0);
#pragma unroll
    for (int j = 0; j < 4; ++j) {
        float inv = __builtin_amdgcn_rsqf(fmaxf(fmaf(A0[j], A0[j], fmaf(A1[j], A1[j], A2[j]*A2[j])), 1e-24f));
        A0[j] *= inv; A1[j] *= inv; A2[j] *= inv;
        inv = __builtin_amdgcn_rsqf(fmaxf(fmaf(B0[j], B0[j], fmaf(B1[j], B1[j], B2[j]*B2[j])), 1e-24f));
        B0[j] *= inv; B1[j] *= inv; B2[j] *= inv;
    }
    // split into f32x2 pairs: [group][pair]  group: 0=A coords, 1=B coords
    f32x2 ax0 = {A0[0], A0[1]}, ax1 = {A0[2], A0[3]};
    f32x2 ay0 = {A1[0], A1[1]}, ay1 = {A1[2], A1[3]};
    f32x2 az0 = {A2[0], A2[1]}, az1 = {A2[2], A2[3]};
    f32x2 bx0 = {B0[0], B0[1]}, bx1 = {B0[2], B0[3]};
    f32x2 by0 = {B1[0], B1[1]}, by1 = {B1[2], B1[3]};
    f32x2 bz0 = {B2[0], B2[1]}, bz1 = {B2[2], B2[3]};

    const float vx = verts[row * 3 + 0];
    const float vy = verts[row * 3 + 1];
    const float vz = verts[row * 3 + 2];

    int gs[NNB];
    {
        const i32x4* np4 = reinterpret_cast<const i32x4*>(nbr + (size_t)row * NNB);
#pragma unroll
        for (int t = 0; t < 5; ++t) {
            const i32x4 g4 = np4[t];
            gs[t*4+0] = g4[0]; gs[t*4+1] = g4[1]; gs[t*4+2] = g4[2]; gs[t*4+3] = g4[3];
        }
    }

    const f32x2 zero = {0.f, 0.f};
    f32x2 mA0 = {-INFINITY, -INFINITY}, mA1 = mA0, mB0 = mA0, mB1 = mA0;
    float d2max = 0.f;
    const float* supB = support + (size_t)bV * SCOL + c0;

#pragma unroll
    for (int j = 0; j < NNB; ++j) {
        const int g = bV + gs[j];
        const float px = verts[g * 3 + 0];
        const float py = verts[g * 3 + 1];
        const float pz = verts[g * 3 + 2];
        const float dx = px - vx, dy = py - vy, dz = pz - vz;
        const float d2 = fmaf(dx, dx, fmaf(dy, dy, dz * dz));
        d2max = fmaxf(d2max, d2);
        const float inv = __builtin_amdgcn_rsqf(fmaxf(d2, 1e-24f));  // == 1/max(dist,1e-12)
        const f32x2 nX = {dx * inv, dx * inv};
        const f32x2 nY = {dy * inv, dy * inv};
        const f32x2 nZ = {dz * inv, dz * inv};

        const float* sg = supB + (size_t)gs[j] * SCOL;
        const f32x4 s0 = *(const f32x4*)(sg);
        const f32x4 s1 = *(const f32x4*)(sg + OUTC);
        const f32x2 s0lo = {s0[0], s0[1]}, s0hi = {s0[2], s0[3]};
        const f32x2 s1lo = {s1[0], s1[1]}, s1hi = {s1[2], s1[3]};

        const f32x2 tA0 = emax(efma(nZ, az0, efma(nY, ay0, nX * ax0)), zero);
        const f32x2 tA1 = emax(efma(nZ, az1, efma(nY, ay1, nX * ax1)), zero);
        const f32x2 tB0 = emax(efma(nZ, bz0, efma(nY, by0, nX * bx0)), zero);
        const f32x2 tB1 = emax(efma(nZ, bz1, efma(nY, by1, nX * bx1)), zero);
        mA0 = emax(mA0, tA0 * s0lo);
        mA1 = emax(mA1, tA1 * s0hi);
        mB0 = emax(mB0, tB0 * s1lo);
        mB1 = emax(mB1, tB1 * s1hi);
    }

    const f32x4 cc = *(const f32x4*)(center + (size_t)row * OUTC + c0);
    const f32x2 f01 = (f32x2){cc[0], cc[1]} + mA0 + mB0;
    const f32x2 f23 = (f32x2){cc[2], cc[3]} + mA1 + mB1;
    bf16x4 fx;
    fx[0] = (__bf16)f01[0]; fx[1] = (__bf16)f01[1];
    fx[2] = (__bf16)f23[0]; fx[3] = (__bf16)f23[1];
    *(bf16x4*)(Xb + (size_t)row * OUTC + c0) = fx;
    if (sl == 0) dmaxv[row] = sqrtf(d2max);
}

// ---------------------------------------------------------------------------
// K3: out = fuse @ Wm1^T + dmax*w2 + mlp_b (MFMA bf16, K=128).
// Block = 4 waves: wave w -> rows blk*32 + (w>>1)*16, cols (w&1)*64 (4 tiles).
// ---------------------------------------------------------------------------
__global__ __launch_bounds__(256) void k_out(const __bf16* __restrict__ Xb,
                                             const __bf16* __restrict__ Wm1b,
                                             const float* __restrict__ dmaxv,
                                             const float* __restrict__ w2,
                                             const float* __restrict__ mb,
                                             float* __restrict__ out) {
    const int wid = threadIdx.x >> 6, lane = threadIdx.x & 63;
    const int ln = lane & 15, lg = lane >> 4;
    const int row0 = blockIdx.x * 32 + (wid >> 1) * 16;
    const int cb = (wid & 1) * 64;

    const __bf16* ap = Xb + (size_t)(row0 + ln) * OUTC + lg * 8;
    bf16x8 a[4];
#pragma unroll
    for (int kf = 0; kf < 4; ++kf) a[kf] = *(const bf16x8*)(ap + kf * 32);

    f32x4 acc[4];
#pragma unroll
    for (int t = 0; t < 4; ++t) acc[t] = (f32x4)0.f;

    const __bf16* bp = Wm1b + (size_t)(cb + ln) * OUTC + lg * 8;
#pragma unroll
    for (int t = 0; t < 4; ++t) {
#pragma unroll
        for (int kf = 0; kf < 4; ++kf) {
            const bf16x8 b = *(const bf16x8*)(bp + t * 16 * OUTC + kf * 32);
            acc[t] = __builtin_amdgcn_mfma_f32_16x16x32_bf16(a[kf], b, acc[t], 0, 0, 0);
        }
    }

    float dm[4];
#pragma unroll
    for (int r = 0; r < 4; ++r) dm[r] = dmaxv[row0 + lg * 4 + r];

#pragma unroll
    for (int t = 0; t < 4; ++t) {
        const int col = cb + t * 16 + ln;
        const float w2c = w2[col];
        const float bb = mb[col];
#pragma unroll
        for (int r = 0; r < 4; ++r)
            out[(size_t)(row0 + lg * 4 + r) * OUTC + col] = fmaf(dm[r], w2c, acc[t][r] + bb);
    }
}

// ---------------------------------------------------------------------------
extern "C" void kernel_launch(void* const* d_in, const int* in_sizes, int n_in,
                              void* d_out, int out_size, void* d_ws, size_t ws_size,
                              hipStream_t stream) {
    const int*   nbr   = (const int*)  d_in[0];
    const float* verts = (const float*)d_in[1];
    const float* fm    = (const float*)d_in[2];
    const float* W     = (const float*)d_in[3];
    const float* bias  = (const float*)d_in[4];
    const float* dirs  = (const float*)d_in[5];
    const float* dw    = (const float*)d_in[6];
    const float* Wm    = (const float*)d_in[7];
    const float* mb    = (const float*)d_in[8];
    float* out = (float*)d_out;

    // workspace layout (all 16B-aligned)
    float*  center  = (float*)d_ws;                         // 16384*128 f32
    float*  support = center + (size_t)ROWS * OUTC;         // 16384*256 f32
    __bf16* Xb      = (__bf16*)(support + (size_t)ROWS * SCOL);  // 16384*128 bf16
    float*  dmaxv   = (float*)(Xb + (size_t)ROWS * OUTC);   // 16384 f32
    __bf16* WTb     = (__bf16*)(dmaxv + ROWS);              // 384*64 bf16
    __bf16* Wm1b    = WTb + NCOL * INC;                     // 128*128 bf16
    float*  w2      = (float*)(Wm1b + OUTC * OUTC);         // 128 f32

    k_prep <<<161,        256, 0, stream>>>(W, Wm, dw, WTb, Wm1b, w2);
    k_feat <<<ROWS / 32,  256, 0, stream>>>(fm, WTb, bias, center, support);
    k_neigh<<<ROWS / 8,   256, 0, stream>>>(nbr, verts, dirs, center, support, Xb, dmaxv);
    k_out  <<<ROWS / 32,  256, 0, stream>>>(Xb, Wm1b, dmaxv, w2, mb, out);
}